// Round 1
// baseline (4738.523 us; speedup 1.0000x reference)
//
#include <hip/hip_runtime.h>
#include <hip/hip_bf16.h>
#include <math.h>

// Problem constants: B=2, LX=1024, DIM=2048, KV=1024, H=16, HD=128, KHD=64,
// GT=8, S=GH*GW=512, LY=4096, BT=B*GT=16.

// ---------------------------------------------------------------------------
// block-wide reduce of two scalars (blockDim.x == 256 assumed, 4 waves of 64)
// ---------------------------------------------------------------------------
__device__ __forceinline__ void block_reduce2(float& s0, float& s1) {
#pragma unroll
  for (int off = 32; off > 0; off >>= 1) {
    s0 += __shfl_down(s0, off);
    s1 += __shfl_down(s1, off);
  }
  __shared__ float red0[4], red1[4];
  int lane = threadIdx.x & 63, w = threadIdx.x >> 6;
  if (lane == 0) { red0[w] = s0; red1[w] = s1; }
  __syncthreads();
  s0 = red0[0] + red0[1] + red0[2] + red0[3];
  s1 = red1[0] + red1[1] + red1[2] + red1[3];
}

// ---------------------------------------------------------------------------
// Generic f32 GEMM: C[M,N] = A[M,K] @ W[N,K]^T + bias[N]
// 128x128 tile, BK=16, 256 threads, 8x8 per thread. N, K multiples of 128/16.
// ---------------------------------------------------------------------------
__global__ __launch_bounds__(256) void gemm_bt_f32(
    const float* __restrict__ A, const float* __restrict__ W,
    const float* __restrict__ bias, float* __restrict__ C,
    int M, int N, int K)
{
  __shared__ float As[16][132];
  __shared__ float Ws[16][132];
  const int tid = threadIdx.x;
  const int tx = tid & 15, ty = tid >> 4;
  const int m0 = blockIdx.y * 128, n0 = blockIdx.x * 128;
  float acc[8][8];
#pragma unroll
  for (int i = 0; i < 8; ++i)
#pragma unroll
    for (int j = 0; j < 8; ++j) acc[i][j] = 0.f;

  for (int k0 = 0; k0 < K; k0 += 16) {
#pragma unroll
    for (int u = 0; u < 2; ++u) {
      int idx = tid + u * 256;            // 0..511
      int rr = idx >> 2, c4 = (idx & 3) << 2;
      int gm = m0 + rr;
      float4 av = make_float4(0.f, 0.f, 0.f, 0.f);
      if (gm < M) av = *(const float4*)&A[(size_t)gm * K + k0 + c4];
      As[c4 + 0][rr] = av.x; As[c4 + 1][rr] = av.y;
      As[c4 + 2][rr] = av.z; As[c4 + 3][rr] = av.w;
      int gn = n0 + rr;
      float4 wv = *(const float4*)&W[(size_t)gn * K + k0 + c4];
      Ws[c4 + 0][rr] = wv.x; Ws[c4 + 1][rr] = wv.y;
      Ws[c4 + 2][rr] = wv.z; Ws[c4 + 3][rr] = wv.w;
    }
    __syncthreads();
#pragma unroll
    for (int kk = 0; kk < 16; ++kk) {
      float4 a0 = *(const float4*)&As[kk][ty * 8];
      float4 a1 = *(const float4*)&As[kk][ty * 8 + 4];
      float4 b0 = *(const float4*)&Ws[kk][tx * 4];
      float4 b1 = *(const float4*)&Ws[kk][64 + tx * 4];
      float a[8] = {a0.x, a0.y, a0.z, a0.w, a1.x, a1.y, a1.z, a1.w};
      float b[8] = {b0.x, b0.y, b0.z, b0.w, b1.x, b1.y, b1.z, b1.w};
#pragma unroll
      for (int i = 0; i < 8; ++i)
#pragma unroll
        for (int j = 0; j < 8; ++j)
          acc[i][j] = fmaf(a[i], b[j], acc[i][j]);
    }
    __syncthreads();
  }
  float4 bs0 = *(const float4*)&bias[n0 + tx * 4];
  float4 bs1 = *(const float4*)&bias[n0 + 64 + tx * 4];
#pragma unroll
  for (int i = 0; i < 8; ++i) {
    int gm = m0 + ty * 8 + i;
    if (gm < M) {
      float4 o0 = make_float4(acc[i][0] + bs0.x, acc[i][1] + bs0.y,
                              acc[i][2] + bs0.z, acc[i][3] + bs0.w);
      float4 o1 = make_float4(acc[i][4] + bs1.x, acc[i][5] + bs1.y,
                              acc[i][6] + bs1.z, acc[i][7] + bs1.w);
      *(float4*)&C[(size_t)gm * N + n0 + tx * 4] = o0;
      *(float4*)&C[(size_t)gm * N + n0 + 64 + tx * 4] = o1;
    }
  }
}

// ---------------------------------------------------------------------------
// qp[j] = probe . mha_in_w[j,:] + b[j], j in [0,1024)   (wq = rows 0..1023)
// ---------------------------------------------------------------------------
__global__ void pool_qp_kernel(const float* __restrict__ probe,
                               const float* __restrict__ w,
                               const float* __restrict__ b,
                               float* __restrict__ qp)
{
  int j = blockIdx.x * blockDim.x + threadIdx.x;
  if (j >= 1024) return;
  const float* wr = w + (size_t)j * 1024;
  float s = 0.f;
  for (int i = 0; i < 1024; i += 4) {
    float4 p = *(const float4*)&probe[i];
    float4 ww = *(const float4*)&wr[i];
    s += p.x * ww.x + p.y * ww.y + p.z * ww.z + p.w * ww.w;
  }
  qp[j] = s + b[j];
}

// ---------------------------------------------------------------------------
// Pooling attention: per (bt, h): scores over 512 keys of dim 64, softmax,
// ctx[bt, h*64+d] = sum_s p_s * vp[bt,s,h,d]
// ---------------------------------------------------------------------------
__global__ __launch_bounds__(256) void pool_attn_kernel(
    const float* __restrict__ qp, const float* __restrict__ kp,
    const float* __restrict__ vp, float* __restrict__ ctx)
{
  int bt = blockIdx.x, h = blockIdx.y;
  int tid = threadIdx.x;
  __shared__ float qs[64];
  __shared__ float sc[512];
  __shared__ float red[4][64];
  if (tid < 64) qs[tid] = qp[h * 64 + tid];
  __syncthreads();
#pragma unroll
  for (int u = 0; u < 2; ++u) {
    int k = tid + u * 256;
    const float* kr = kp + ((size_t)(bt * 512 + k)) * 1024 + h * 64;
    float s = 0.f;
#pragma unroll
    for (int d = 0; d < 64; d += 4) {
      float4 kv = *(const float4*)&kr[d];
      s += qs[d] * kv.x + qs[d + 1] * kv.y + qs[d + 2] * kv.z + qs[d + 3] * kv.w;
    }
    sc[k] = s * 0.125f;  // 1/sqrt(64)
  }
  __syncthreads();
  float m = -1e30f;
  for (int k = 0; k < 512; ++k) m = fmaxf(m, sc[k]);
  float l = 0.f;
  for (int k = 0; k < 512; ++k) l += __expf(sc[k] - m);
  int d = tid & 63, chunk = tid >> 6;
  float acc = 0.f;
  for (int k = chunk * 128; k < (chunk + 1) * 128; ++k)
    acc += __expf(sc[k] - m) * vp[((size_t)(bt * 512 + k)) * 1024 + h * 64 + d];
  red[chunk][d] = acc;
  __syncthreads();
  if (tid < 64) {
    float v = red[0][tid] + red[1][tid] + red[2][tid] + red[3][tid];
    ctx[(size_t)bt * 1024 + h * 64 + tid] = v / l;
  }
}

// ---------------------------------------------------------------------------
// Row LayerNorm (width template), optional affine
// ---------------------------------------------------------------------------
template <int WIDTH, bool AFFINE>
__global__ __launch_bounds__(256) void ln_kernel(
    const float* __restrict__ in, float* __restrict__ out,
    const float* __restrict__ w, const float* __restrict__ b, float eps)
{
  constexpr int E = WIDTH / 1024;  // float4s per thread
  int row = blockIdx.x;
  const float* rp = in + (size_t)row * WIDTH;
  float4 v[E];
  float s = 0.f, s2 = 0.f;
#pragma unroll
  for (int e = 0; e < E; ++e) {
    v[e] = *(const float4*)&rp[threadIdx.x * 4 + e * 1024];
    s += v[e].x + v[e].y + v[e].z + v[e].w;
    s2 += v[e].x * v[e].x + v[e].y * v[e].y + v[e].z * v[e].z + v[e].w * v[e].w;
  }
  block_reduce2(s, s2);
  float mean = s * (1.0f / WIDTH);
  float var = s2 * (1.0f / WIDTH) - mean * mean;
  float rs = rsqrtf(var + eps);
  float* op = out + (size_t)row * WIDTH;
#pragma unroll
  for (int e = 0; e < E; ++e) {
    int d = threadIdx.x * 4 + e * 1024;
    float4 o;
    o.x = (v[e].x - mean) * rs;
    o.y = (v[e].y - mean) * rs;
    o.z = (v[e].z - mean) * rs;
    o.w = (v[e].w - mean) * rs;
    if (AFFINE) {
      float4 w4 = *(const float4*)&w[d];
      float4 b4 = *(const float4*)&b[d];
      o.x = o.x * w4.x + b4.x; o.y = o.y * w4.y + b4.y;
      o.z = o.z * w4.z + b4.z; o.w = o.w * w4.w + b4.w;
    }
    *(float4*)&op[d] = o;
  }
}

// ---------------------------------------------------------------------------
// temb row = interp of pooled along grid_t (t=8 -> 1024), then silu
// ---------------------------------------------------------------------------
__global__ __launch_bounds__(256) void interp_silu_kernel(
    const float* __restrict__ pooled, float* __restrict__ out)
{
  int row = blockIdx.x;               // b*1024 + i
  int b = row >> 10, i = row & 1023;
  float coord = (i + 0.5f) * (8.0f / 1024.0f) - 0.5f;
  coord = fminf(fmaxf(coord, 0.0f), 7.0f);
  float fl = floorf(coord);
  int lo = (int)fl;
  int hi = lo + 1; if (hi > 7) hi = 7;
  float w = coord - fl;
  const float* plo = pooled + (size_t)(b * 8 + lo) * 1024;
  const float* phi = pooled + (size_t)(b * 8 + hi) * 1024;
  int d = threadIdx.x * 4;
  float4 a = *(const float4*)&plo[d];
  float4 c = *(const float4*)&phi[d];
  float4 o;
  float zx = a.x * (1.f - w) + c.x * w;
  float zy = a.y * (1.f - w) + c.y * w;
  float zz = a.z * (1.f - w) + c.z * w;
  float zw = a.w * (1.f - w) + c.w * w;
  o.x = zx / (1.f + __expf(-zx));
  o.y = zy / (1.f + __expf(-zy));
  o.z = zz / (1.f + __expf(-zz));
  o.w = zw / (1.f + __expf(-zw));
  *(float4*)&out[(size_t)row * 1024 + d] = o;
}

// ---------------------------------------------------------------------------
// xln = LN(x, eps=1e-5, no affine) * (1 + scale) + shift, scale/shift from temb
// ---------------------------------------------------------------------------
__global__ __launch_bounds__(256) void x_mod_ln_kernel(
    const float* __restrict__ x, const float* __restrict__ temb,
    float* __restrict__ out)
{
  int row = blockIdx.x;  // b*1024 + l, width 2048
  const float* rp = x + (size_t)row * 2048;
  float4 v[2];
  float s = 0.f, s2 = 0.f;
#pragma unroll
  for (int e = 0; e < 2; ++e) {
    v[e] = *(const float4*)&rp[threadIdx.x * 4 + e * 1024];
    s += v[e].x + v[e].y + v[e].z + v[e].w;
    s2 += v[e].x * v[e].x + v[e].y * v[e].y + v[e].z * v[e].z + v[e].w * v[e].w;
  }
  block_reduce2(s, s2);
  float mean = s * (1.0f / 2048.0f);
  float var = s2 * (1.0f / 2048.0f) - mean * mean;
  float rs = rsqrtf(var + 1e-5f);
  const float* te = temb + (size_t)row * 4096;
  float* op = out + (size_t)row * 2048;
#pragma unroll
  for (int e = 0; e < 2; ++e) {
    int d = threadIdx.x * 4 + e * 1024;
    float4 sc = *(const float4*)&te[d];
    float4 sh = *(const float4*)&te[2048 + d];
    float4 o;
    o.x = (v[e].x - mean) * rs * (1.f + sc.x) + sh.x;
    o.y = (v[e].y - mean) * rs * (1.f + sc.y) + sh.y;
    o.z = (v[e].z - mean) * rs * (1.f + sc.z) + sh.z;
    o.w = (v[e].w - mean) * rs * (1.f + sc.w) + sh.w;
    *(float4*)&op[d] = o;
  }
}

// ---------------------------------------------------------------------------
// In-place rmsnorm (over 2048) + RoPE (per 128-dim head, cos/sin per row).
// ---------------------------------------------------------------------------
__global__ __launch_bounds__(256) void rms_rope_kernel(
    float* __restrict__ buf, const float* __restrict__ rw,
    const float* __restrict__ cs, const float* __restrict__ sn)
{
  int row = blockIdx.x;
  float* rp = buf + (size_t)row * 2048;
  __shared__ float rb[2048];
  float s2 = 0.f;
#pragma unroll
  for (int e = 0; e < 2; ++e) {
    int d = threadIdx.x * 4 + e * 1024;
    float4 v = *(const float4*)&rp[d];
    *(float4*)&rb[d] = v;
    s2 += v.x * v.x + v.y * v.y + v.z * v.z + v.w * v.w;
  }
  float dummy = 0.f;
  block_reduce2(s2, dummy);  // contains __syncthreads: rb is visible after
  float rs = rsqrtf(s2 * (1.0f / 2048.0f) + 1e-6f);
#pragma unroll
  for (int e = 0; e < 2; ++e) {
    int d = threadIdx.x * 4 + e * 1024;
    int hd = d & 127;                    // all 4 comps same half (4-aligned)
    bool lowhalf = hd < 64;
    int pd = lowhalf ? d + 64 : d - 64;
    float4 w4 = *(const float4*)&rw[d];
    float4 wp = *(const float4*)&rw[pd];
    float4 c4 = *(const float4*)&cs[(size_t)row * 128 + hd];
    float4 s4 = *(const float4*)&sn[(size_t)row * 128 + hd];
    float ux = rb[d + 0] * rs * w4.x, uy = rb[d + 1] * rs * w4.y;
    float uz = rb[d + 2] * rs * w4.z, uw = rb[d + 3] * rs * w4.w;
    float px = rb[pd + 0] * rs * wp.x, py = rb[pd + 1] * rs * wp.y;
    float pz = rb[pd + 2] * rs * wp.z, pw = rb[pd + 3] * rs * wp.w;
    float sgn = lowhalf ? -1.f : 1.f;
    float4 o;
    o.x = ux * c4.x + sgn * px * s4.x;
    o.y = uy * c4.y + sgn * py * s4.y;
    o.z = uz * c4.z + sgn * pz * s4.z;
    o.w = uw * c4.w + sgn * pw * s4.w;
    *(float4*)&rp[d] = o;
  }
}

// ---------------------------------------------------------------------------
// Flash attention, f32: grid (LX/32, H, B), 256 threads.
// thread t: row r=t>>3 of Q-tile, lane-group g=t&7 owns dims {4g+32i+j}.
// ---------------------------------------------------------------------------
__global__ __launch_bounds__(256) void flash_attn_kernel(
    const float* __restrict__ Q, const float* __restrict__ K,
    const float* __restrict__ V, float* __restrict__ O)
{
  int qt = blockIdx.x, h = blockIdx.y, b = blockIdx.z;
  int tid = threadIdx.x;
  int r = tid >> 3, g = tid & 7;
  __shared__ float4 Ks[32 * 32];
  __shared__ float4 Vs[32 * 32];
  size_t qrow = (size_t)b * 1024 + qt * 32 + r;
  const float* qp = Q + qrow * 2048 + h * 128;
  float4 q4[4];
#pragma unroll
  for (int i = 0; i < 4; ++i) q4[i] = *(const float4*)&qp[g * 4 + 32 * i];
  float4 acc[4];
#pragma unroll
  for (int i = 0; i < 4; ++i) acc[i] = make_float4(0.f, 0.f, 0.f, 0.f);
  float m_run = -1e30f, l_run = 0.f;
  const float scale = 0.08838834764831845f;  // 1/sqrt(128)

  for (int kt = 0; kt < 128; ++kt) {
#pragma unroll
    for (int u = 0; u < 4; ++u) {
      int idx = tid + u * 256;             // 0..1023
      int key = idx >> 5, d4 = idx & 31;
      size_t krow = (size_t)b * 4096 + kt * 32 + key;
      Ks[idx] = *(const float4*)&K[krow * 2048 + h * 128 + d4 * 4];
      Vs[idx] = *(const float4*)&V[krow * 2048 + h * 128 + d4 * 4];
    }
    __syncthreads();
    float s[32];
#pragma unroll
    for (int c = 0; c < 32; ++c) {
      float p = 0.f;
#pragma unroll
      for (int i = 0; i < 4; ++i) {
        float4 kv = Ks[c * 32 + g + 8 * i];
        p += q4[i].x * kv.x + q4[i].y * kv.y + q4[i].z * kv.z + q4[i].w * kv.w;
      }
      p += __shfl_xor(p, 1);
      p += __shfl_xor(p, 2);
      p += __shfl_xor(p, 4);
      s[c] = p * scale;
    }
    float mt = s[0];
#pragma unroll
    for (int c = 1; c < 32; ++c) mt = fmaxf(mt, s[c]);
    float m_new = fmaxf(m_run, mt);
    float corr = __expf(m_run - m_new);
    l_run *= corr;
#pragma unroll
    for (int i = 0; i < 4; ++i) {
      acc[i].x *= corr; acc[i].y *= corr; acc[i].z *= corr; acc[i].w *= corr;
    }
#pragma unroll
    for (int c = 0; c < 32; ++c) {
      float pc = __expf(s[c] - m_new);
      l_run += pc;
#pragma unroll
      for (int i = 0; i < 4; ++i) {
        float4 vv = Vs[c * 32 + g + 8 * i];
        acc[i].x += pc * vv.x; acc[i].y += pc * vv.y;
        acc[i].z += pc * vv.z; acc[i].w += pc * vv.w;
      }
    }
    m_run = m_new;
    __syncthreads();
  }
  float inv = 1.0f / l_run;
  float* op = O + qrow * 2048 + h * 128;
#pragma unroll
  for (int i = 0; i < 4; ++i) {
    float4 o = make_float4(acc[i].x * inv, acc[i].y * inv,
                           acc[i].z * inv, acc[i].w * inv);
    *(float4*)&op[g * 4 + 32 * i] = o;
  }
}

// ---------------------------------------------------------------------------
// launch
// ---------------------------------------------------------------------------
extern "C" void kernel_launch(void* const* d_in, const int* in_sizes, int n_in,
                              void* d_out, int out_size, void* d_ws, size_t ws_size,
                              hipStream_t stream)
{
  const float* x        = (const float*)d_in[0];
  const float* y        = (const float*)d_in[1];
  const float* x_cos    = (const float*)d_in[2];
  const float* x_sin    = (const float*)d_in[3];
  const float* y_cos    = (const float*)d_in[4];
  const float* y_sin    = (const float*)d_in[5];
  const float* probe    = (const float*)d_in[6];
  const float* mha_in_w = (const float*)d_in[7];
  const float* mha_in_b = (const float*)d_in[8];
  const float* mha_out_w= (const float*)d_in[9];
  const float* mha_out_b= (const float*)d_in[10];
  const float* pool_ln_w= (const float*)d_in[11];
  const float* pool_ln_b= (const float*)d_in[12];
  const float* ada_w    = (const float*)d_in[13];
  const float* ada_b    = (const float*)d_in[14];
  const float* ynorm_w  = (const float*)d_in[15];
  const float* ynorm_b  = (const float*)d_in[16];
  const float* q_w      = (const float*)d_in[17];
  const float* q_b      = (const float*)d_in[18];
  const float* k_w      = (const float*)d_in[19];
  const float* k_b      = (const float*)d_in[20];
  const float* v_w      = (const float*)d_in[21];
  const float* v_b      = (const float*)d_in[22];
  const float* o_w      = (const float*)d_in[23];
  const float* o_b      = (const float*)d_in[24];
  const float* rms_q_w  = (const float*)d_in[25];
  const float* rms_k_w  = (const float*)d_in[26];

  float* ws = (float*)d_ws;
  // workspace arena (floats). Aliased regions: kp<->temb, vp<->yln, xln<->attn_out
  float* kp     = ws;                      // 8,388,608  (16,512,1024)
  float* temb   = ws;                      //            (2048, 4096) after kp dead
  float* vp     = ws + 8388608;            // 8,388,608
  float* yln    = vp;                      //            (8192, 1024) after vp dead
  float* xln    = ws + 16777216;           // 4,194,304  (2048, 2048)
  float* attno  = xln;                     //            (2048, 2048) after xln dead
  float* qbuf   = ws + 20971520;           // 4,194,304
  float* kbuf   = ws + 25165824;           // 16,777,216 (8192, 2048)
  float* vbuf   = ws + 41943040;           // 16,777,216
  float* asilu  = ws + 58720256;           // 2,097,152  (2048, 1024)
  float* qp     = ws + 60817408;           // 1,024
  float* ctx    = ws + 60818432;           // 16,384
  float* plraw  = ws + 60834816;           // 16,384
  float* pooled = ws + 60851200;           // 16,384
  float* outf   = (float*)d_out;

  dim3 blk(256);
  // --- pooling path ---
  pool_qp_kernel<<<dim3(4), blk, 0, stream>>>(probe, mha_in_w, mha_in_b, qp);
  gemm_bt_f32<<<dim3(8, 64), blk, 0, stream>>>(y, mha_in_w + 1024 * 1024,
                                               mha_in_b + 1024, kp, 8192, 1024, 1024);
  gemm_bt_f32<<<dim3(8, 64), blk, 0, stream>>>(y, mha_in_w + 2 * 1024 * 1024,
                                               mha_in_b + 2048, vp, 8192, 1024, 1024);
  pool_attn_kernel<<<dim3(16, 16), blk, 0, stream>>>(qp, kp, vp, ctx);
  gemm_bt_f32<<<dim3(8, 1), blk, 0, stream>>>(ctx, mha_out_w, mha_out_b, plraw,
                                              16, 1024, 1024);
  ln_kernel<1024, true><<<dim3(16), blk, 0, stream>>>(plraw, pooled,
                                                      pool_ln_w, pool_ln_b, 1e-6f);
  interp_silu_kernel<<<dim3(2048), blk, 0, stream>>>(pooled, asilu);
  gemm_bt_f32<<<dim3(32, 16), blk, 0, stream>>>(asilu, ada_w, ada_b, temb,
                                                2048, 4096, 1024);
  // --- main path ---
  ln_kernel<1024, true><<<dim3(8192), blk, 0, stream>>>(y, yln, ynorm_w, ynorm_b, 1e-6f);
  x_mod_ln_kernel<<<dim3(2048), blk, 0, stream>>>(x, temb, xln);
  gemm_bt_f32<<<dim3(16, 16), blk, 0, stream>>>(xln, q_w, q_b, qbuf, 2048, 2048, 2048);
  gemm_bt_f32<<<dim3(16, 64), blk, 0, stream>>>(yln, k_w, k_b, kbuf, 8192, 2048, 1024);
  gemm_bt_f32<<<dim3(16, 64), blk, 0, stream>>>(yln, v_w, v_b, vbuf, 8192, 2048, 1024);
  rms_rope_kernel<<<dim3(2048), blk, 0, stream>>>(qbuf, rms_q_w, x_cos, x_sin);
  rms_rope_kernel<<<dim3(8192), blk, 0, stream>>>(kbuf, rms_k_w, y_cos, y_sin);
  flash_attn_kernel<<<dim3(32, 16, 2), blk, 0, stream>>>(qbuf, kbuf, vbuf, attno);
  gemm_bt_f32<<<dim3(16, 16), blk, 0, stream>>>(attno, o_w, o_b, outf, 2048, 2048, 2048);
}